// Round 10
// baseline (296.300 us; speedup 1.0000x reference)
//
#include <hip/hip_runtime.h>
#include <math.h>

#define NN 20000      // nodes
#define NE 320000     // edges (without self loops)
#define NT 340000     // edges + self loops
#define NG 64         // graphs
#define HB 1329       // (NT+255)/256 scatter blocks

// k_prep block ranges
#define PB_HS   1                 // block 0: fused histogram+scan (single block)
#define PB_W2   129               // [1,129): W2 transpose->bf16
#define PB_A2   131               // [129,131): a2p GEMV
#define PB_SZ   163               // [131,163): zero sums (32 blocks x 1024 floats)
#define PB_TOT  (PB_SZ + NN / 4)  // + 5000 h1 blocks

using short8  = __attribute__((ext_vector_type(8))) short;   // 8 x bf16 (4 VGPRs)
using float4v = __attribute__((ext_vector_type(4))) float;   // MFMA accumulator

__device__ __forceinline__ float lrelu(float v) { return v > 0.f ? v : 0.2f * v; }
__device__ __forceinline__ float elu1(float v)  { return v > 0.f ? v : (expf(v) - 1.f); }
__device__ __forceinline__ unsigned short f2bf(float f) {
    unsigned u = __float_as_uint(f);
    u += 0x7FFFu + ((u >> 16) & 1u);   // round to nearest even
    return (unsigned short)(u >> 16);
}
__device__ __forceinline__ float bf2f(unsigned short s) {
    return __uint_as_float(((unsigned)s) << 16);
}

__device__ __forceinline__ int esrc(const int* ei, int e) { return e < NE ? ei[e] : (e - NE); }
__device__ __forceinline__ int edst(const int* ei, int e) { return e < NE ? ei[NE + e] : (e - NE); }

// ---------- D1: fused prep ----------
// block 0: LDS histogram (packed ushort, init=1 for self-loops) + scan -> rowstart/cursor/gstart
// blocks [1,129): W2bfT; [129,131): a2p GEMV; [131,163): zero sums; rest: h1 transform + logits
__global__ void k_prep(const int* __restrict__ ei, const int* __restrict__ batch,
                       int* __restrict__ rowstart, int* __restrict__ cursor,
                       int* __restrict__ gstart,
                       const float* __restrict__ W2, unsigned short* __restrict__ W2bfT,
                       const float* __restrict__ as2, const float* __restrict__ ad2,
                       float* __restrict__ a2ps, float* __restrict__ a2pd,
                       float* __restrict__ sums,
                       const float* __restrict__ x, const float* __restrict__ W1,
                       const float* __restrict__ as1, const float* __restrict__ ad1,
                       unsigned short* __restrict__ h1bf, float* __restrict__ al_s,
                       float* __restrict__ al_d) {
    __shared__ unsigned degp[NN / 2];   // packed ushort counts, 40 KB
    __shared__ int part[256];
    int tid = threadIdx.x;
    if (blockIdx.x == 0) {
        // init packed counts to 1 (self-loop per node)
        for (int i = tid; i < NN / 2; i += 256) degp[i] = 0x00010001u;
        __syncthreads();
        // histogram dst (int4 loads of ei[NE..2NE))
        const int4* dp = (const int4*)(ei + NE);
        for (int i = tid; i < NE / 4; i += 256) {
            int4 v = dp[i];
            atomicAdd(&degp[v.x >> 1], 1u << ((v.x & 1) * 16));
            atomicAdd(&degp[v.y >> 1], 1u << ((v.y & 1) * 16));
            atomicAdd(&degp[v.z >> 1], 1u << ((v.z & 1) * 16));
            atomicAdd(&degp[v.w >> 1], 1u << ((v.w & 1) * 16));
        }
        __syncthreads();
        // scan: thread t owns rows [t*80, t*80+80) (t<250)
        int base = tid * 80;
        int s = 0;
        if (base < NN) {
            for (int i = 0; i < 80; ++i) {
                int idx = base + i;
                s += (degp[idx >> 1] >> ((idx & 1) * 16)) & 0xFFFF;
            }
        }
        part[tid] = s;
        __syncthreads();
        for (int o = 1; o < 256; o <<= 1) {
            int v = (tid >= o) ? part[tid - o] : 0;
            __syncthreads();
            part[tid] += v;
            __syncthreads();
        }
        if (base < NN) {
            int run = (tid == 0) ? 0 : part[tid - 1];
            for (int i = 0; i < 80; ++i) {
                int idx = base + i;
                int d = (degp[idx >> 1] >> ((idx & 1) * 16)) & 0xFFFF;
                rowstart[idx] = run;
                cursor[idx] = run;
                run += d;
            }
        }
        if (tid == 0) rowstart[NN] = NT;
        if (tid <= NG) {  // gstart[t] = first node with batch >= t (batch sorted)
            int lo = 0, hi = NN;
            while (lo < hi) {
                int mid = (lo + hi) >> 1;
                if (batch[mid] < tid) lo = mid + 1; else hi = mid;
            }
            gstart[tid] = lo;
        }
        return;
    }
    if (blockIdx.x < PB_W2) {
        int t = (blockIdx.x - PB_HS) * 256 + tid;  // t = n*64 + k
        int k = t & 63, n = t >> 6;
        W2bfT[t] = f2bf(W2[k * 512 + n]);
        return;
    }
    if (blockIdx.x < PB_A2) {
        // a2p[k] = sum_j W2[k][j] * a[j]   (64x512 GEMV)
        __shared__ float pp[4][64];
        const float* av = (blockIdx.x == PB_W2) ? as2 : ad2;
        float* outp     = (blockIdx.x == PB_W2) ? a2ps : a2pd;
        int k = tid & 63, seg = tid >> 6;
        float s = 0.f;
        for (int j = seg * 128; j < seg * 128 + 128; ++j)
            s = fmaf(W2[k * 512 + j], av[j], s);
        pp[seg][k] = s;
        __syncthreads();
        if (tid < 64) outp[tid] = pp[0][tid] + pp[1][tid] + pp[2][tid] + pp[3][tid];
        return;
    }
    if (blockIdx.x < PB_SZ) {
        int idx = (blockIdx.x - PB_A2) * 1024 + tid * 4;
        *(float4*)(sums + idx) = make_float4(0.f, 0.f, 0.f, 0.f);
        return;
    }
    int n = (blockIdx.x - PB_SZ) * 4 + (tid >> 6);
    int j = tid & 63;
    float x0 = x[n * 3 + 0], x1 = x[n * 3 + 1], x2 = x[n * 3 + 2];
    float v = fmaf(x0, W1[j], fmaf(x1, W1[64 + j], x2 * W1[128 + j]));
    h1bf[n * 64 + j] = f2bf(v);
    float ps = v * as1[j];
    float pd = v * ad1[j];
    for (int o = 4; o >= 1; o >>= 1) {
        ps += __shfl_xor(ps, o, 8);
        pd += __shfl_xor(pd, o, 8);
    }
    if ((j & 7) == 0) {
        al_s[n * 8 + (j >> 3)] = ps;
        al_d[n * 8 + (j >> 3)] = pd;
    }
}

// ---------- D2: CSR scatter ----------
__global__ void k_scatter(const int* __restrict__ ei, int* __restrict__ cursor,
                          int* __restrict__ csr_src) {
    int t = blockIdx.x * blockDim.x + threadIdx.x;
    if (t >= NT) return;
    int d = edst(ei, t), s = esrc(ei, t);
    int pos = atomicAdd(&cursor[d], 1);
    csr_src[pos] = s;
}

// ---------- D3: fused layer-1 softmax + aggregate + bias + elu -> o1bf; layer-2 logits ----------
__global__ void k_l1(const int* __restrict__ rowstart, const int* __restrict__ csr_src,
                     const float* __restrict__ al_s, const float* __restrict__ al_d,
                     const unsigned short* __restrict__ h1bf, const float* __restrict__ b1,
                     const float* __restrict__ a2ps, const float* __restrict__ a2pd,
                     unsigned short* __restrict__ o1bf, float* __restrict__ al_s2,
                     float* __restrict__ al_d2) {
    int n = blockIdx.x * 4 + (threadIdx.x >> 6);
    int j = threadIdx.x & 63;  // channel
    int h = j >> 3;            // head
    float ald = al_d[n * 8 + h];
    int start = rowstart[n], end = rowstart[n + 1];
    float m = -1e30f;
    for (int e = start + (j & 7); e < end; e += 8) {
        m = fmaxf(m, lrelu(al_s[csr_src[e] * 8 + h] + ald));
    }
    for (int o = 4; o >= 1; o >>= 1) m = fmaxf(m, __shfl_xor(m, o, 8));
    float denom = 0.f, acc = 0.f;
    int e = start;
    for (; e + 1 < end; e += 2) {
        int s0 = csr_src[e], s1 = csr_src[e + 1];
        float ex0 = __expf(lrelu(al_s[s0 * 8 + h] + ald) - m);
        float ex1 = __expf(lrelu(al_s[s1 * 8 + h] + ald) - m);
        denom += ex0 + ex1;
        acc = fmaf(ex0, bf2f(h1bf[s0 * 64 + j]), fmaf(ex1, bf2f(h1bf[s1 * 64 + j]), acc));
    }
    if (e < end) {
        int s0 = csr_src[e];
        float ex0 = __expf(lrelu(al_s[s0 * 8 + h] + ald) - m);
        denom += ex0;
        acc = fmaf(ex0, bf2f(h1bf[s0 * 64 + j]), acc);
    }
    float v = elu1(acc / denom + b1[j]);   // f32 o1 value
    o1bf[n * 64 + j] = f2bf(v);
    float ps = v * a2ps[j];
    float pd = v * a2pd[j];
    for (int o = 32; o >= 1; o >>= 1) {
        ps += __shfl_xor(ps, o, 64);
        pd += __shfl_xor(pd, o, 64);
    }
    if (j == 0) { al_s2[n] = ps; al_d2[n] = pd; }
}

// ---------- D4: fused layer-2 softmax-agg (64-dim) + MFMA @W2 + bias + elu + pool ----------
// 16 nodes/block, 512 threads (8 waves). Phase A: wave w aggregates nodes w*2,w*2+1 -> LDS bf16.
// Phase B: MFMA (A from LDS, B from W2bfT), elu, graph-masked pool -> atomics into sums.
__global__ void k_l2gemm(const int* __restrict__ rowstart, const int* __restrict__ csr_src,
                         const float* __restrict__ al_s2, const float* __restrict__ al_d2,
                         const unsigned short* __restrict__ o1bf,
                         const unsigned short* __restrict__ W2bfT,
                         const float* __restrict__ b2, const int* __restrict__ batch,
                         float* __restrict__ sums) {
    __shared__ unsigned short lagg[16][72];   // padded rows: 144B stride breaks bank aliasing
    int n0 = blockIdx.x * 16;
    int w = threadIdx.x >> 6, lane = threadIdx.x & 63;
#pragma unroll
    for (int i = 0; i < 2; ++i) {
        int r = w * 2 + i;
        int n = n0 + r;
        float ald = al_d2[n];
        int start = rowstart[n], end = rowstart[n + 1];
        float m = -1e30f;
        for (int e = start + lane; e < end; e += 64) {
            m = fmaxf(m, lrelu(al_s2[csr_src[e]] + ald));
        }
        for (int o = 32; o >= 1; o >>= 1) m = fmaxf(m, __shfl_xor(m, o, 64));
        float denom = 0.f, acc = 0.f;
        int e = start;
        for (; e + 1 < end; e += 2) {
            int s0 = csr_src[e], s1 = csr_src[e + 1];
            float ex0 = __expf(lrelu(al_s2[s0] + ald) - m);
            float ex1 = __expf(lrelu(al_s2[s1] + ald) - m);
            denom += ex0 + ex1;
            acc = fmaf(ex0, bf2f(o1bf[s0 * 64 + lane]),
                       fmaf(ex1, bf2f(o1bf[s1 * 64 + lane]), acc));
        }
        if (e < end) {
            int s0 = csr_src[e];
            float ex0 = __expf(lrelu(al_s2[s0] + ald) - m);
            denom += ex0;
            acc = fmaf(ex0, bf2f(o1bf[s0 * 64 + lane]), acc);
        }
        lagg[r][lane] = f2bf(acc / denom);
    }
    __syncthreads();
    // phase B: A[m=lane&15][k=quad*8+j] from LDS; B[k][n=lane&15] from W2bfT (n-major).
    int mcol = lane & 15;
    int q = lane >> 4;
    short8 a0 = *(const short8*)&lagg[mcol][q * 8];
    short8 a1 = *(const short8*)&lagg[mcol][32 + q * 8];
    int gmin = batch[n0], gmax = batch[n0 + 15];
    int batchq[4];
#pragma unroll
    for (int r = 0; r < 4; ++r) batchq[r] = batch[n0 + q * 4 + r];
#pragma unroll
    for (int t = 0; t < 4; ++t) {
        int c = w * 64 + t * 16 + mcol;
        const unsigned short* bp = W2bfT + c * 64 + q * 8;
        short8 b0 = *(const short8*)bp;
        short8 b1 = *(const short8*)(bp + 32);
        float4v acc = {0.f, 0.f, 0.f, 0.f};
        acc = __builtin_amdgcn_mfma_f32_16x16x32_bf16(a0, b0, acc, 0, 0, 0);
        acc = __builtin_amdgcn_mfma_f32_16x16x32_bf16(a1, b1, acc, 0, 0, 0);
        float bias = b2[c];
        float val[4];
#pragma unroll
        for (int r = 0; r < 4; ++r) val[r] = elu1(acc[r] + bias);
        for (int g = gmin; g <= gmax; ++g) {
            float s = 0.f;
#pragma unroll
            for (int r = 0; r < 4; ++r) s += (batchq[r] == g) ? val[r] : 0.f;
            s += __shfl_xor(s, 16, 64);   // reduce across the 4 quads
            s += __shfl_xor(s, 32, 64);
            if (q == 0) atomicAdd(&sums[g * 512 + c], s);
        }
    }
}

// ---------- D5: final GEMM: out[g][j] = (sums[g] @ Wo[:,j]) / cnt[g] + bo[j] ----------
__global__ void k_final(const float* __restrict__ sums, const int* __restrict__ gstart,
                        const float* __restrict__ Wo, const float* __restrict__ bo,
                        float* __restrict__ out) {
    __shared__ float sp[512];
    int g = blockIdx.x >> 3;
    int j = (blockIdx.x & 7) * 64 + threadIdx.x;  // 64 threads
    for (int k = threadIdx.x; k < 512; k += 64) sp[k] = sums[g * 512 + k];
    __syncthreads();
    float c = (float)(gstart[g + 1] - gstart[g]);
    float inv = 1.f / (c > 0.f ? c : 1.f);
    float acc = 0.f;
    for (int k = 0; k < 512; ++k) acc = fmaf(sp[k], Wo[k * 512 + j], acc);
    out[g * 512 + j] = fmaf(acc, inv, bo[j]);
}

extern "C" void kernel_launch(void* const* d_in, const int* in_sizes, int n_in,
                              void* d_out, int out_size, void* d_ws, size_t ws_size,
                              hipStream_t stream) {
    const float* x     = (const float*)d_in[0];
    const int*   ei    = (const int*)d_in[1];    // [2, NE]
    const int*   batch = (const int*)d_in[2];    // [NN] sorted
    const float* W1    = (const float*)d_in[3];
    const float* as1   = (const float*)d_in[4];
    const float* ad1   = (const float*)d_in[5];
    const float* b1    = (const float*)d_in[6];
    const float* W2    = (const float*)d_in[7];
    const float* as2   = (const float*)d_in[8];
    const float* ad2   = (const float*)d_in[9];
    const float* b2    = (const float*)d_in[10];
    const float* Wo    = (const float*)d_in[11];
    const float* bo    = (const float*)d_in[12];
    float* out = (float*)d_out;

    // ---- workspace arena (4-byte units) ----
    float* w = (float*)d_ws;
    unsigned short* h1bf  = (unsigned short*)(w + 0);        // 640,000 units
    float* al_s1 = w + 640000;     // 160,000
    float* al_d1 = w + 800000;     // 160,000
    unsigned short* o1bf  = (unsigned short*)(w + 960000);   // 640,000 units (byte 3,840,000: 16B aligned)
    unsigned short* W2bfT = (unsigned short*)(w + 1600000);  // 16,384 units (byte 6,400,000: 16B aligned)
    float* a2ps  = w + 1616384;    // 64
    float* a2pd  = w + 1616448;    // 64
    float* al_s2 = w + 1616512;    // 20,000
    float* al_d2 = w + 1636512;    // 20,000
    int*   rowstart = (int*)(w + 1656512);   // 20,001
    int*   cursor   = (int*)(w + 1676516);   // 20,000
    int*   csr_src  = (int*)(w + 1696516);   // 340,000
    int*   gstart   = (int*)(w + 2036516);   // 65
    float* sums     = w + 2036584;           // 32,768 (byte 8,146,336: 16B aligned; zeroed by prep)
    // end: 2,069,352 units ≈ 8.3 MB

    k_prep   <<<PB_TOT, 256, 0, stream>>>(ei, batch, rowstart, cursor, gstart,
                                          W2, W2bfT, as2, ad2, a2ps, a2pd, sums,
                                          x, W1, as1, ad1, h1bf, al_s1, al_d1);
    k_scatter<<<HB, 256, 0, stream>>>(ei, cursor, csr_src);
    k_l1     <<<NN / 4, 256, 0, stream>>>(rowstart, csr_src, al_s1, al_d1, h1bf, b1,
                                          a2ps, a2pd, o1bf, al_s2, al_d2);
    k_l2gemm <<<NN / 16, 512, 0, stream>>>(rowstart, csr_src, al_s2, al_d2, o1bf,
                                           W2bfT, b2, batch, sums);
    k_final  <<<NG * 8, 64, 0, stream>>>(sums, gstart, Wo, bo, out);
}